// Round 1
// baseline (91.050 us; speedup 1.0000x reference)
//
#include <hip/hip_runtime.h>
#include <math.h>

#define EEG_CH 64
#define WIN    128
#define KW     9
#define OUTW   120
#define NOUT   10
#define ROWP   132          // padded LDS row stride (8B-aligned even-w float2s)

// cross-block handoff lives in module globals (d_ws no longer used):
// g_msum[o*2+h] = per-(o,h) conv means; g_ctr = monotonic completion counter.
__device__ float        g_msum[2 * NOUT];
__device__ unsigned int g_ctr = 0;

__device__ __forceinline__ float readlane_f(float v, int l) {
    return __int_as_float(__builtin_amdgcn_readlane(__float_as_int(v), l));
}

// One fused kernel: each block owns one output channel o.
// Each block redundantly computes the SE path (cheap, removes k1->k2 node dep);
// the 10th block to finish (monotonic atomic counter) runs the FCN epilogue.
__launch_bounds__(256)
__global__ void cnn_fused(const float* __restrict__ xg,
                          const float* __restrict__ w1g, const float* __restrict__ b1g,
                          const float* __restrict__ w2g, const float* __restrict__ b2g,
                          const float* __restrict__ cwg, const float* __restrict__ cbg,
                          const float* __restrict__ f1w, const float* __restrict__ f1b,
                          const float* __restrict__ f2w, const float* __restrict__ f2b,
                          float* __restrict__ out)
{
    __shared__ float w1l[64 * 64];   // transposed: w1l[i*64+j] = w1g[j*64+i]
    __shared__ float w2l[64 * 64];
    __shared__ float xl[64 * ROWP];  // eeg rows (x rows 1..64), padded
    __shared__ float rnorm[66];
    __shared__ float nums[2];
    __shared__ float sef[128];       // se_flat [h][i]
    __shared__ float part[4][OUTW];  // per-wave partial pre-relu sums
    __shared__ float msh[2];
    __shared__ int   sflag;
    __shared__ float msums[2 * NOUT];

    const int tid  = threadIdx.x;
    const int wv   = tid >> 6;       // 0..3
    const int lane = tid & 63;
    const int o    = blockIdx.x;

    // ---- phase A: stage everything (all independent, issue back-to-back) ----
    // eeg rows -> LDS (64 rows x 32 float4)
    for (int t = tid; t < 2048; t += 256) {
        const int row = t >> 5, c4 = t & 31;
        const float4 v = *(const float4*)(xg + (row + 1) * WIN + c4 * 4);
        *(float4*)(xl + row * ROWP + c4 * 4) = v;
    }
    // w1/w2 transposed -> LDS (2 x 1024 float4 tasks)
    for (int t = tid; t < 2048; t += 256) {
        const int j  = t & 63;
        const int i4 = (t >> 6) & 15;
        const float* __restrict__ src = (t < 1024) ? w1g : w2g;
        float* __restrict__ dst = (t < 1024) ? w1l : w2l;
        const float4 v = *(const float4*)(src + j * 64 + i4 * 4);
        dst[(i4 * 4 + 0) * 64 + j] = v.x;
        dst[(i4 * 4 + 1) * 64 + j] = v.y;
        dst[(i4 * 4 + 2) * 64 + j] = v.z;
        dst[(i4 * 4 + 3) * 64 + j] = v.w;
    }
    // lane-resident conv weights for this wave's 32-channel chunk
    const int h = wv >> 1, ihalf = wv & 1;
    const int chbase = ihalf * 32;
    float wl[KW];
    if (lane < 32) {
        const float* __restrict__ cwo = cwg + o * (EEG_CH * KW) + (chbase + lane) * KW;
        #pragma unroll
        for (int k = 0; k < KW; ++k) wl[k] = cwo[k];
    }
    // row norms straight from global (L2-hot; 66 rows over 4 waves)
    for (int row = wv; row < 66; row += 4) {
        const float v0 = xg[row * WIN + lane];
        const float v1 = xg[row * WIN + 64 + lane];
        float s = v0 * v0 + v1 * v1;
        for (int off = 32; off > 0; off >>= 1) s += __shfl_xor(s, off, 64);
        if (lane == 0) rnorm[row] = sqrtf(s);
    }
    if (wv < 2) {
        const int wrow = (wv == 0) ? 0 : 65;
        float p = xg[WIN + lane]      * xg[wrow * WIN + lane]
                + xg[WIN + 64 + lane] * xg[wrow * WIN + 64 + lane];
        for (int off = 32; off > 0; off >>= 1) p += __shfl_xor(p, off, 64);
        if (lane == 0) nums[wv] = p;
    }
    __syncthreads();

    // ---- phase B: SE MLP (waves 0,1; identical math to verified k1) ----
    if (wv < 2) {
        const int r = wv, j = lane;
        const float er = nums[r] / (rnorm[j + 1] * (r == 0 ? rnorm[0] : rnorm[65]));
        float acc = b1g[j];
        #pragma unroll
        for (int i = 0; i < 64; ++i)
            acc += readlane_f(er, i) * w1l[i * 64 + j];
        const float hv = tanhf(acc);
        float acc2 = b2g[j];
        #pragma unroll
        for (int i = 0; i < 64; ++i)
            acc2 += readlane_f(hv, i) * w2l[i * 64 + j];
        const float sg = 1.f / (1.f + expf(-acc2));
        float mx = sg;
        for (int off = 32; off > 0; off >>= 1) mx = fmaxf(mx, __shfl_xor(mx, off, 64));
        const float e = expf(sg - mx);
        float ss = e;
        for (int off = 32; off > 0; off >>= 1) ss += __shfl_xor(ss, off, 64);
        sef[r * 64 + j] = e / ss;
    }
    __syncthreads();

    // ---- phase C: conv + relu + mean (identical math to verified k2) ----
    float sl = 0.f;
    if (lane < 32) sl = sef[h * 64 + chbase + lane];

    const int wbase = (lane < 60) ? 2 * lane : 116;   // lanes 60-63 redundant
    float q0 = 0.f, q1 = 0.f;
    #pragma unroll 4
    for (int ii = 0; ii < 32; ++ii) {
        const int i = chbase + ii;
        const float2* xp = (const float2*)(xl + i * ROWP + wbase);
        const float2 x0 = xp[0], x1 = xp[1], x2 = xp[2], x3 = xp[3], x4 = xp[4];
        const float xw[10] = { x0.x, x0.y, x1.x, x1.y, x2.x, x2.y,
                               x3.x, x3.y, x4.x, x4.y };
        float wk[KW];
        #pragma unroll
        for (int k = 0; k < KW; ++k) wk[k] = readlane_f(wl[k], ii);
        const float s = readlane_f(sl, ii);
        float p0 = 0.f, p1 = 0.f;
        #pragma unroll
        for (int k = 0; k < KW; ++k) {
            p0 += xw[k]     * wk[k];
            p1 += xw[k + 1] * wk[k];
        }
        q0 += s * p0;
        q1 += s * p1;
    }
    if (lane < 60) {
        *(float2*)(&part[wv][wbase]) = make_float2(q0, q1);
    }
    __syncthreads();

    if (wv < 2) {
        const float bo = cbg[o];
        float r = 0.f;
        if (lane < 60) {
            const float v0 = part[wv * 2][wbase]     + part[wv * 2 + 1][wbase]     + bo;
            const float v1 = part[wv * 2][wbase + 1] + part[wv * 2 + 1][wbase + 1] + bo;
            r = fmaxf(v0, 0.f) + fmaxf(v1, 0.f);
        }
        for (int off = 32; off > 0; off >>= 1) r += __shfl_xor(r, off, 64);
        if (lane == 0) msh[wv] = r * (1.0f / OUTW);
    }
    __syncthreads();

    // ---- phase D: publish msum; 10th finisher (monotonic ctr) runs the FCN ----
    if (tid == 0) {
        __hip_atomic_store(&g_msum[o * 2 + 0], msh[0], __ATOMIC_RELAXED, __HIP_MEMORY_SCOPE_AGENT);
        __hip_atomic_store(&g_msum[o * 2 + 1], msh[1], __ATOMIC_RELAXED, __HIP_MEMORY_SCOPE_AGENT);
        // ACQ_REL RMW: releases the two stores above device-wide; acquires all
        // prior blocks' releases. old%10==9 <=> this block is the 10th of this
        // iteration (exactly 10 adds per launch; counter never reset -> robust
        // across graph replays and rocprof re-execution; no spin, no deadlock).
        const unsigned old = __hip_atomic_fetch_add(&g_ctr, 1u, __ATOMIC_ACQ_REL, __HIP_MEMORY_SCOPE_AGENT);
        sflag = (old % 10u == 9u) ? 1 : 0;
    }
    __syncthreads();

    if (sflag) {   // block-uniform -> barriers inside are legal
        if (tid < 2 * NOUT)
            msums[tid] = __hip_atomic_load(&g_msum[tid], __ATOMIC_ACQUIRE, __HIP_MEMORY_SCOPE_AGENT);
        __syncthreads();
        if (tid < 64) {
            float h2v = 0.f;
            if (lane < 10) {
                float a = f1b[lane];
                #pragma unroll
                for (int p = 0; p < 20; ++p) a += msums[p] * f1w[lane * 20 + p];
                h2v = 1.f / (1.f + expf(-a));
            }
            float t0 = (lane < 10) ? h2v * f2w[lane]      : 0.f;
            float t1 = (lane < 10) ? h2v * f2w[10 + lane] : 0.f;
            for (int off = 32; off > 0; off >>= 1) {
                t0 += __shfl_xor(t0, off, 64);
                t1 += __shfl_xor(t1, off, 64);
            }
            if (lane == 0) {
                const float l0 = f2b[0] + t0, l1 = f2b[1] + t1;
                const float m  = fmaxf(l0, l1);
                const float e0 = expf(l0 - m), e1 = expf(l1 - m);
                out[0] = e0 / (e0 + e1);
                out[1] = e1 / (e0 + e1);
            }
        }
    }
}

extern "C" void kernel_launch(void* const* d_in, const int* in_sizes, int n_in,
                              void* d_out, int out_size, void* d_ws, size_t ws_size,
                              hipStream_t stream) {
    (void)in_sizes; (void)n_in; (void)ws_size; (void)out_size; (void)d_ws;
    const float* xg  = (const float*)d_in[0];
    const float* w1  = (const float*)d_in[1];
    const float* b1  = (const float*)d_in[2];
    const float* w2  = (const float*)d_in[3];
    const float* b2  = (const float*)d_in[4];
    const float* cw  = (const float*)d_in[5];
    const float* cb  = (const float*)d_in[6];
    const float* f1w = (const float*)d_in[7];
    const float* f1b = (const float*)d_in[8];
    const float* f2w = (const float*)d_in[9];
    const float* f2b = (const float*)d_in[10];
    float* out = (float*)d_out;

    cnn_fused<<<dim3(NOUT), dim3(256), 0, stream>>>(xg, w1, b1, w2, b2,
                                                    cw, cb, f1w, f1b, f2w, f2b, out);
}

// Round 2
// 84.544 us; speedup vs baseline: 1.0769x; 1.0769x over previous
//
#include <hip/hip_runtime.h>
#include <math.h>

#define EEG_CH 64
#define WIN    128
#define KW     9
#define OUTW   120
#define NOUT   10
#define ROWP   132          // padded LDS row stride (8B-aligned even-w float2s)

// cross-block handoff lives in module globals (d_ws not used):
// g_msum[o*2+h] = per-(o,h) conv means; g_ctr = monotonic completion counter.
__device__ float        g_msum[2 * NOUT];
__device__ unsigned int g_ctr = 0;

__device__ __forceinline__ float readlane_f(float v, int l) {
    return __int_as_float(__builtin_amdgcn_readlane(__float_as_int(v), l));
}

// One fused kernel node: each block owns one output channel o, 16 waves.
// Phase A (staging + norms) is spread over all 16 waves; phases B/C keep the
// exact reduction structures of the verified 3-kernel version (absmax 0.0).
// The 10th block to finish (monotonic atomic counter) runs the FCN epilogue.
__launch_bounds__(1024)
__global__ void cnn_fused(const float* __restrict__ xg,
                          const float* __restrict__ w1g, const float* __restrict__ b1g,
                          const float* __restrict__ w2g, const float* __restrict__ b2g,
                          const float* __restrict__ cwg, const float* __restrict__ cbg,
                          const float* __restrict__ f1w, const float* __restrict__ f1b,
                          const float* __restrict__ f2w, const float* __restrict__ f2b,
                          float* __restrict__ out)
{
    __shared__ float w1l[64 * 64];   // transposed: w1l[i*64+j] = w1g[j*64+i]
    __shared__ float w2l[64 * 64];
    __shared__ float xl[64 * ROWP];  // eeg rows (x rows 1..64), padded
    __shared__ float rnorm[66];
    __shared__ float nums[2];
    __shared__ float sef[128];       // se_flat [h][i]
    __shared__ float part[4][OUTW];  // per-wave partial pre-relu sums
    __shared__ float msh[2];
    __shared__ int   sflag;
    __shared__ float msums[2 * NOUT];

    const int tid  = threadIdx.x;
    const int wv   = tid >> 6;       // 0..15
    const int lane = tid & 63;
    const int o    = blockIdx.x;

    // ---- phase A: staging + norms, spread over 16 waves ----
    // eeg rows -> LDS (64 rows x 32 float4): 2 iters/thread
    for (int t = tid; t < 2048; t += 1024) {
        const int row = t >> 5, c4 = t & 31;
        const float4 v = *(const float4*)(xg + (row + 1) * WIN + c4 * 4);
        *(float4*)(xl + row * ROWP + c4 * 4) = v;
    }
    // w1/w2 transposed -> LDS (2 x 1024 float4 tasks): 2 iters/thread
    for (int t = tid; t < 2048; t += 1024) {
        const int j  = t & 63;
        const int i4 = (t >> 6) & 15;
        const float* __restrict__ src = (t < 1024) ? w1g : w2g;
        float* __restrict__ dst = (t < 1024) ? w1l : w2l;
        const float4 v = *(const float4*)(src + j * 64 + i4 * 4);
        dst[(i4 * 4 + 0) * 64 + j] = v.x;
        dst[(i4 * 4 + 1) * 64 + j] = v.y;
        dst[(i4 * 4 + 2) * 64 + j] = v.z;
        dst[(i4 * 4 + 3) * 64 + j] = v.w;
    }
    // conv weights lane-resident for the 4 conv waves (32-ch chunk each)
    const int h = wv >> 1, ihalf = wv & 1;   // meaningful for wv<4
    const int chbase = ihalf * 32;
    float wl[KW];
    if (wv < 4 && lane < 32) {
        const float* __restrict__ cwo = cwg + o * (EEG_CH * KW) + (chbase + lane) * KW;
        #pragma unroll
        for (int k = 0; k < KW; ++k) wl[k] = cwo[k];
    }
    // row norms straight from global (L2-hot), <=5 rows per wave,
    // identical per-row reduction tree as the verified kernel
    for (int row = wv; row < 66; row += 16) {
        const float v0 = xg[row * WIN + lane];
        const float v1 = xg[row * WIN + 64 + lane];
        float s = v0 * v0 + v1 * v1;
        for (int off = 32; off > 0; off >>= 1) s += __shfl_xor(s, off, 64);
        if (lane == 0) rnorm[row] = sqrtf(s);
    }
    if (wv < 2) {
        const int wrow = (wv == 0) ? 0 : 65;
        float p = xg[WIN + lane]      * xg[wrow * WIN + lane]
                + xg[WIN + 64 + lane] * xg[wrow * WIN + 64 + lane];
        for (int off = 32; off > 0; off >>= 1) p += __shfl_xor(p, off, 64);
        if (lane == 0) nums[wv] = p;
    }
    __syncthreads();

    // ---- phase B: SE MLP (waves 0,1; identical math to verified version) ----
    if (wv < 2) {
        const int r = wv, j = lane;
        const float er = nums[r] / (rnorm[j + 1] * (r == 0 ? rnorm[0] : rnorm[65]));
        float acc = b1g[j];
        #pragma unroll
        for (int i = 0; i < 64; ++i)
            acc += readlane_f(er, i) * w1l[i * 64 + j];
        const float hv = tanhf(acc);
        float acc2 = b2g[j];
        #pragma unroll
        for (int i = 0; i < 64; ++i)
            acc2 += readlane_f(hv, i) * w2l[i * 64 + j];
        const float sg = 1.f / (1.f + expf(-acc2));
        float mx = sg;
        for (int off = 32; off > 0; off >>= 1) mx = fmaxf(mx, __shfl_xor(mx, off, 64));
        const float e = expf(sg - mx);
        float ss = e;
        for (int off = 32; off > 0; off >>= 1) ss += __shfl_xor(ss, off, 64);
        sef[r * 64 + j] = e / ss;
    }
    __syncthreads();

    // ---- phase C: conv + relu + mean (waves 0-3; identical to verified) ----
    const int wbase = (lane < 60) ? 2 * lane : 116;   // lanes 60-63 redundant
    if (wv < 4) {
        float sl = 0.f;
        if (lane < 32) sl = sef[h * 64 + chbase + lane];

        float q0 = 0.f, q1 = 0.f;
        #pragma unroll 4
        for (int ii = 0; ii < 32; ++ii) {
            const int i = chbase + ii;
            const float2* xp = (const float2*)(xl + i * ROWP + wbase);
            const float2 x0 = xp[0], x1 = xp[1], x2 = xp[2], x3 = xp[3], x4 = xp[4];
            const float xw[10] = { x0.x, x0.y, x1.x, x1.y, x2.x, x2.y,
                                   x3.x, x3.y, x4.x, x4.y };
            float wk[KW];
            #pragma unroll
            for (int k = 0; k < KW; ++k) wk[k] = readlane_f(wl[k], ii);
            const float s = readlane_f(sl, ii);
            float p0 = 0.f, p1 = 0.f;
            #pragma unroll
            for (int k = 0; k < KW; ++k) {
                p0 += xw[k]     * wk[k];
                p1 += xw[k + 1] * wk[k];
            }
            q0 += s * p0;
            q1 += s * p1;
        }
        if (lane < 60) {
            *(float2*)(&part[wv][wbase]) = make_float2(q0, q1);
        }
    }
    __syncthreads();

    if (wv < 2) {
        const float bo = cbg[o];
        float r = 0.f;
        if (lane < 60) {
            const float v0 = part[wv * 2][wbase]     + part[wv * 2 + 1][wbase]     + bo;
            const float v1 = part[wv * 2][wbase + 1] + part[wv * 2 + 1][wbase + 1] + bo;
            r = fmaxf(v0, 0.f) + fmaxf(v1, 0.f);
        }
        for (int off = 32; off > 0; off >>= 1) r += __shfl_xor(r, off, 64);
        if (lane == 0) msh[wv] = r * (1.0f / OUTW);
    }
    __syncthreads();

    // ---- phase D: publish msum; 10th finisher (monotonic ctr) runs the FCN ----
    if (tid == 0) {
        __hip_atomic_store(&g_msum[o * 2 + 0], msh[0], __ATOMIC_RELAXED, __HIP_MEMORY_SCOPE_AGENT);
        __hip_atomic_store(&g_msum[o * 2 + 1], msh[1], __ATOMIC_RELAXED, __HIP_MEMORY_SCOPE_AGENT);
        // ACQ_REL RMW: releases the two stores above device-wide; acquires all
        // prior blocks' releases. old%10==9 <=> this block is the 10th of this
        // launch (exactly 10 adds per launch; counter never reset -> robust
        // across graph replays and rocprof re-execution; no spin, no deadlock).
        const unsigned old = __hip_atomic_fetch_add(&g_ctr, 1u, __ATOMIC_ACQ_REL, __HIP_MEMORY_SCOPE_AGENT);
        sflag = (old % 10u == 9u) ? 1 : 0;
    }
    __syncthreads();

    if (sflag) {   // block-uniform -> barriers inside are legal
        if (tid < 2 * NOUT)
            msums[tid] = __hip_atomic_load(&g_msum[tid], __ATOMIC_ACQUIRE, __HIP_MEMORY_SCOPE_AGENT);
        __syncthreads();
        if (tid < 64) {
            float h2v = 0.f;
            if (lane < 10) {
                float a = f1b[lane];
                #pragma unroll
                for (int p = 0; p < 20; ++p) a += msums[p] * f1w[lane * 20 + p];
                h2v = 1.f / (1.f + expf(-a));
            }
            float t0 = (lane < 10) ? h2v * f2w[lane]      : 0.f;
            float t1 = (lane < 10) ? h2v * f2w[10 + lane] : 0.f;
            for (int off = 32; off > 0; off >>= 1) {
                t0 += __shfl_xor(t0, off, 64);
                t1 += __shfl_xor(t1, off, 64);
            }
            if (lane == 0) {
                const float l0 = f2b[0] + t0, l1 = f2b[1] + t1;
                const float m  = fmaxf(l0, l1);
                const float e0 = expf(l0 - m), e1 = expf(l1 - m);
                out[0] = e0 / (e0 + e1);
                out[1] = e1 / (e0 + e1);
            }
        }
    }
}

extern "C" void kernel_launch(void* const* d_in, const int* in_sizes, int n_in,
                              void* d_out, int out_size, void* d_ws, size_t ws_size,
                              hipStream_t stream) {
    (void)in_sizes; (void)n_in; (void)ws_size; (void)out_size; (void)d_ws;
    const float* xg  = (const float*)d_in[0];
    const float* w1  = (const float*)d_in[1];
    const float* b1  = (const float*)d_in[2];
    const float* w2  = (const float*)d_in[3];
    const float* b2  = (const float*)d_in[4];
    const float* cw  = (const float*)d_in[5];
    const float* cb  = (const float*)d_in[6];
    const float* f1w = (const float*)d_in[7];
    const float* f1b = (const float*)d_in[8];
    const float* f2w = (const float*)d_in[9];
    const float* f2b = (const float*)d_in[10];
    float* out = (float*)d_out;

    cnn_fused<<<dim3(NOUT), dim3(1024), 0, stream>>>(xg, w1, b1, w2, b2,
                                                     cw, cb, f1w, f1b, f2w, f2b, out);
}